// Round 8
// baseline (120.288 us; speedup 1.0000x reference)
//
#include <hip/hip_runtime.h>

#define WH 9216
#define NF 64
#define NC 32
#define NH 8
#define IMGW 96
#define IMGH 96
#define PW 98
#define PPLANE 9604
#define L2E 1.4426950408889634f
#define DEFER 11.5f   // log2 units

typedef float f32x4 __attribute__((ext_vector_type(4)));
typedef short short8 __attribute__((ext_vector_type(8)));

__device__ inline short bf16_bits(float x) {
  __bf16 h = (__bf16)x;
  return __builtin_bit_cast(short, h);
}
__device__ inline float bf16_round(float x) { return (float)(__bf16)x; }

// ---------------- kernel A (fused): qsk (blocks 0..575) + padX (576..876) + wpack (877) ----
__global__ __launch_bounds__(256, 2) void prep_kernel(
    const float* __restrict__ X, const float* __restrict__ WQ_task,
    const float* __restrict__ BQ_task, const float* __restrict__ WK_task,
    const float* __restrict__ BK_task, const float* __restrict__ WQ_t1,
    const float* __restrict__ WQ_x, const float* __restrict__ BQ,
    const float* __restrict__ WK_x, const float* __restrict__ BK,
    const float* __restrict__ prevQ, const float* __restrict__ Wc,
    const float* __restrict__ WV_task,
    short* __restrict__ qfrag, short* __restrict__ kfrag,
    unsigned short* __restrict__ padXT, short8* __restrict__ wfrag)
{
  const int bid = blockIdx.x;
  const int t = threadIdx.x;
  if (bid < 576) {
    const int lane = t & 63;
    const int w2 = t >> 6;
    const int fh = w2 & 1, sub = w2 >> 1;
    const int h = lane >> 4;
    const int T = bid;
    const int wh = T * 16 + (lane & 15);
    const int f0 = fh * 32 + 8 * h + 4 * sub;

    float x[4];
    #pragma unroll
    for (int e = 0; e < 4; ++e) x[e] = X[(size_t)(f0 + e) * WH + wh];
    float pq[32];
    #pragma unroll
    for (int a = 0; a < NH; ++a)
      #pragma unroll
      for (int e = 0; e < 4; ++e)
        pq[a * 4 + e] = prevQ[(size_t)(a * 64 + f0 + e) * WH + wh];

    const float4 wkx = *(const float4*)&WK_x[f0];
    const float4 bk  = *(const float4*)&BK[f0];
    const float4 wkt = *(const float4*)&WK_task[f0];
    const float4 bkt = *(const float4*)&BK_task[f0];
    const float4 wqx = *(const float4*)&WQ_x[f0];

    float q[4], k[4], xq[4];
    k[0] = fmaf(wkt.x, fmaxf(fmaf(wkx.x, x[0], bk.x), 0.f), bkt.x);
    k[1] = fmaf(wkt.y, fmaxf(fmaf(wkx.y, x[1], bk.y), 0.f), bkt.y);
    k[2] = fmaf(wkt.z, fmaxf(fmaf(wkx.z, x[2], bk.z), 0.f), bkt.z);
    k[3] = fmaf(wkt.w, fmaxf(fmaf(wkx.w, x[3], bk.w), 0.f), bkt.w);
    xq[0] = wqx.x * x[0]; xq[1] = wqx.y * x[1];
    xq[2] = wqx.z * x[2]; xq[3] = wqx.w * x[3];
    q[0] = q[1] = q[2] = q[3] = 0.f;
    #pragma unroll
    for (int a = 0; a < NH; ++a) {
      const int af0 = a * 64 + f0;
      const float4 w1  = *(const float4*)&WQ_t1[af0];
      const float4 bq  = *(const float4*)&BQ[af0];
      const float4 wqt = *(const float4*)&WQ_task[af0];
      const float4 bqt = *(const float4*)&BQ_task[af0];
      q[0] = fmaf(wqt.x, fmaxf(fmaf(w1.x, pq[a * 4 + 0], xq[0] + bq.x), 0.f), q[0]) + bqt.x;
      q[1] = fmaf(wqt.y, fmaxf(fmaf(w1.y, pq[a * 4 + 1], xq[1] + bq.y), 0.f), q[1]) + bqt.y;
      q[2] = fmaf(wqt.z, fmaxf(fmaf(w1.z, pq[a * 4 + 2], xq[2] + bq.z), 0.f), q[2]) + bqt.z;
      q[3] = fmaf(wqt.w, fmaxf(fmaf(w1.w, pq[a * 4 + 3], xq[3] + bq.w), 0.f), q[3]) + bqt.w;
    }

    short4 qh, ql, kh, klo;
    {
      float qs0 = q[0] * L2E, qs1 = q[1] * L2E, qs2 = q[2] * L2E, qs3 = q[3] * L2E;
      qh.x = bf16_bits(qs0); ql.x = bf16_bits(qs0 - bf16_round(qs0));
      qh.y = bf16_bits(qs1); ql.y = bf16_bits(qs1 - bf16_round(qs1));
      qh.z = bf16_bits(qs2); ql.z = bf16_bits(qs2 - bf16_round(qs2));
      qh.w = bf16_bits(qs3); ql.w = bf16_bits(qs3 - bf16_round(qs3));
      kh.x = bf16_bits(k[0]); klo.x = bf16_bits(k[0] - bf16_round(k[0]));
      kh.y = bf16_bits(k[1]); klo.y = bf16_bits(k[1] - bf16_round(k[1]));
      kh.z = bf16_bits(k[2]); klo.z = bf16_bits(k[2] - bf16_round(k[2]));
      kh.w = bf16_bits(k[3]); klo.w = bf16_bits(k[3] - bf16_round(k[3]));
    }
    const size_t offh = ((size_t)(T * 4 + fh) * 64 + lane) * 8 + sub * 4;
    const size_t offl = ((size_t)(T * 4 + 2 + fh) * 64 + lane) * 8 + sub * 4;
    *(short4*)&qfrag[offh] = qh;
    *(short4*)&qfrag[offl] = ql;
    *(short4*)&kfrag[offh] = kh;
    *(short4*)&kfrag[offl] = klo;
  } else if (bid < 877) {
    const int idx = (bid - 576) * 256 + t;        // fi*9604 + p, fi in [0,8)
    if (idx < 76832) {
      const int fi = idx / PPLANE;
      const int p = idx - fi * PPLANE;
      const int pw = p / PW;
      const int ph = p - pw * PW;
      short8 r;
      if (pw >= 1 && pw <= IMGW && ph >= 1 && ph <= IMGH) {
        const float* src = X + (size_t)fi * 8 * WH + (pw - 1) * IMGH + (ph - 1);
        #pragma unroll
        for (int e = 0; e < 8; ++e) r[e] = bf16_bits(src[(size_t)e * WH]);
      } else {
        #pragma unroll
        for (int e = 0; e < 8; ++e) r[e] = 0;
      }
      *(short8*)&padXT[(size_t)p * 64 + fi * 8] = r;
    }
  } else {
    #pragma unroll
    for (int j = 0; j < 9; ++j) {
      const int ridx = j * 256 + t;               // 2304 records
      const int ct = ridx / 1152;
      const int rem = ridx - ct * 1152;
      const int cc = rem >> 6;
      const int lane = rem & 63;
      const int c = ct * 16 + (lane & 15);
      const int tap = cc >> 1;
      const int f0 = (cc & 1) * 32 + 8 * (lane >> 4);
      const float wv = WV_task[c];
      short8 r;
      #pragma unroll
      for (int e = 0; e < 8; ++e)
        r[e] = bf16_bits(wv * Wc[((size_t)c * NF + f0 + e) * 9 + tap]);
      wfrag[ridx] = r;
    }
  }
}

// ---------------- kernel B: conv via MFMA; one 16-key tile per block, 4-way (Khalf,ct) split ----
__global__ __launch_bounds__(256, 2) void vconv_kernel(
    const unsigned short* __restrict__ padXT, const short8* __restrict__ wfrag,
    const float* __restrict__ bc, const float* __restrict__ WV_task,
    const float* __restrict__ BV_task, short* __restrict__ vfrag)
{
  __shared__ float Vt[2][32][20];
  const int t = threadIdx.x;
  const int lane = t & 63, w = t >> 6;
  const int h = lane >> 4;
  const int ktile = blockIdx.x;                 // 0..575
  const int half = w & 1, ct = w >> 1;
  const int key = ktile * 16 + (lane & 15);
  const int kw = key / IMGH, kh = key - kw * IMGH;

  f32x4 acc = {0.f, 0.f, 0.f, 0.f};
  #pragma unroll
  for (int i = 0; i < 9; ++i) {
    const int cc = half * 9 + i;
    const int tap = cc >> 1;
    const int di = tap / 3, dj = tap - di * 3;
    const int f0 = (cc & 1) * 32 + 8 * h;
    const int sp = (kw + di) * PW + (kh + dj);
    const short8 xf = *(const short8*)&padXT[(size_t)sp * 64 + f0];
    acc = __builtin_amdgcn_mfma_f32_16x16x32_bf16(wfrag[(size_t)(ct * 18 + cc) * 64 + lane],
                                                  xf, acc, 0, 0, 0);
  }
  #pragma unroll
  for (int reg = 0; reg < 4; ++reg)
    Vt[half][ct * 16 + 4 * h + reg][lane & 15] = acc[reg];
  __syncthreads();
  if (t < 128) {
    const int ct2 = t >> 6;
    const int c = ct2 * 16 + (lane & 15);
    const float bias = fmaf(WV_task[c], bc[c], BV_task[c]);
    short4 r;
    #pragma unroll
    for (int j = 0; j < 4; ++j) {
      const int kl = 4 * h + j;                 // baked pi-permutation half
      r[j] = bf16_bits(Vt[0][c][kl] + Vt[1][c][kl] + bias);
    }
    const int ch = ktile >> 1, eh = ktile & 1;
    *(short4*)&vfrag[(((size_t)ch * 2 + ct2) * 64 + lane) * 8 + eh * 4] = r;
  }
}

// ---------------- kernel C: MFMA flash, g=3, per-query m, local-max gate ----
__global__ __launch_bounds__(256, 4) void flash_mfma(
    const short8* __restrict__ qfrag, const short8* __restrict__ kfrag,
    const short8* __restrict__ vfrag, float* __restrict__ part, int cps)
{
  const int t = threadIdx.x;
  const int lane = t & 63, wave = t >> 6;
  const int h = lane >> 4;
  const int qb = blockIdx.x;     // 0..191 (fastest -> all XCDs share live K-slice)
  const int s = blockIdx.y;      // key split

  short8 qf[3][4];
  #pragma unroll
  for (int g = 0; g < 3; ++g)
    #pragma unroll
    for (int tm = 0; tm < 4; ++tm)
      qf[g][tm] = qfrag[((size_t)(qb * 3 + g) * 4 + tm) * 64 + lane];

  f32x4 acc[2][3];
  #pragma unroll
  for (int ct = 0; ct < 2; ++ct)
    #pragma unroll
    for (int g = 0; g < 3; ++g)
      acc[ct][g] = (f32x4){0.f, 0.f, 0.f, 0.f};
  float m[3] = {0.f, 0.f, 0.f};  // per-query running offset (uniform over h-lanes)
  float l[3] = {0.f, 0.f, 0.f};

  const int cpw = cps >> 2;
  const int ch0 = s * cps + wave;
  for (int it = 0; it < cpw; ++it) {
    const int ch = ch0 + it * 4;
    short8 kf[2][4];
    #pragma unroll
    for (int kt = 0; kt < 2; ++kt)
      #pragma unroll
      for (int tm = 0; tm < 4; ++tm)
        kf[kt][tm] = kfrag[((size_t)(2 * ch + kt) * 4 + tm) * 64 + lane];
    const short8 vf0 = vfrag[(size_t)(ch * 2 + 0) * 64 + lane];
    const short8 vf1 = vfrag[(size_t)(ch * 2 + 1) * 64 + lane];

    #pragma unroll
    for (int g = 0; g < 3; ++g) {
      const float nm = -m[g];
      f32x4 st0 = {nm, nm, nm, nm};
      f32x4 st1 = st0;
      st0 = __builtin_amdgcn_mfma_f32_16x16x32_bf16(kf[0][0], qf[g][0], st0, 0, 0, 0);
      st0 = __builtin_amdgcn_mfma_f32_16x16x32_bf16(kf[0][1], qf[g][1], st0, 0, 0, 0);
      st0 = __builtin_amdgcn_mfma_f32_16x16x32_bf16(kf[0][2], qf[g][0], st0, 0, 0, 0);
      st0 = __builtin_amdgcn_mfma_f32_16x16x32_bf16(kf[0][3], qf[g][1], st0, 0, 0, 0);
      st0 = __builtin_amdgcn_mfma_f32_16x16x32_bf16(kf[0][0], qf[g][2], st0, 0, 0, 0);
      st0 = __builtin_amdgcn_mfma_f32_16x16x32_bf16(kf[0][1], qf[g][3], st0, 0, 0, 0);
      st1 = __builtin_amdgcn_mfma_f32_16x16x32_bf16(kf[1][0], qf[g][0], st1, 0, 0, 0);
      st1 = __builtin_amdgcn_mfma_f32_16x16x32_bf16(kf[1][1], qf[g][1], st1, 0, 0, 0);
      st1 = __builtin_amdgcn_mfma_f32_16x16x32_bf16(kf[1][2], qf[g][0], st1, 0, 0, 0);
      st1 = __builtin_amdgcn_mfma_f32_16x16x32_bf16(kf[1][3], qf[g][1], st1, 0, 0, 0);
      st1 = __builtin_amdgcn_mfma_f32_16x16x32_bf16(kf[1][0], qf[g][2], st1, 0, 0, 0);
      st1 = __builtin_amdgcn_mfma_f32_16x16x32_bf16(kf[1][1], qf[g][3], st1, 0, 0, 0);

      // common path: per-lane local max only (no cross-lane ops)
      const float loc = fmaxf(fmaxf(fmaxf(st0[0], st0[1]), fmaxf(st0[2], st0[3])),
                              fmaxf(fmaxf(st1[0], st1[1]), fmaxf(st1[2], st1[3])));
      if (__any(loc > DEFER)) {      // rare: per-query reduce + rescale
        float tr = loc;
        tr = fmaxf(tr, __shfl_xor(tr, 16));
        tr = fmaxf(tr, __shfl_xor(tr, 32));
        const float d = fmaxf(tr, 0.f);
        const float r = exp2f(-d);
        l[g] *= r;
        acc[0][g] *= r;
        acc[1][g] *= r;
        m[g] += d;
        #pragma unroll
        for (int e = 0; e < 4; ++e) { st0[e] -= d; st1[e] -= d; }
      }
      short8 pb;
      float p0[4], p1[4];
      #pragma unroll
      for (int e = 0; e < 4; ++e) {
        p0[e] = exp2f(st0[e]);
        p1[e] = exp2f(st1[e]);
        pb[e] = bf16_bits(p0[e]);
        pb[4 + e] = bf16_bits(p1[e]);
      }
      l[g] += ((p0[0] + p0[1]) + (p0[2] + p0[3])) + ((p1[0] + p1[1]) + (p1[2] + p1[3]));
      acc[0][g] = __builtin_amdgcn_mfma_f32_16x16x32_bf16(vf0, pb, acc[0][g], 0, 0, 0);
      acc[1][g] = __builtin_amdgcn_mfma_f32_16x16x32_bf16(vf1, pb, acc[1][g], 0, 0, 0);
    }
  }

  // epilogue: per-wave partial record {acc[32], m, l}
  const int u = s * 4 + wave;
  #pragma unroll
  for (int g = 0; g < 3; ++g) {
    float lf = l[g] + __shfl_xor(l[g], 16);
    lf += __shfl_xor(lf, 32);
    const int q = qb * 48 + g * 16 + (lane & 15);
    float* base = part + ((size_t)u * WH + q) * 36;
    *(f32x4*)(base + 0 + 4 * h) = acc[0][g];
    *(f32x4*)(base + 16 + 4 * h) = acc[1][g];
    if (h == 0) { base[32] = m[g]; base[33] = lf; }
  }
}

// ---------------- kernel D: single-pass online merge -> out (C, W, H) ----------------
__global__ __launch_bounds__(256) void merge_kernel(
    const float* __restrict__ part, float* __restrict__ out, int units)
{
  const int t = threadIdx.x;
  const int cl = t & 31;
  const int wh = blockIdx.x * 8 + (t >> 5);
  float M = -1e30f, L = 0.f, A = 0.f;
  for (int u = 0; u < units; ++u) {
    const float* base = part + ((size_t)u * WH + wh) * 36;
    const float mu = base[32];
    const float lu = base[33];
    const float au = base[cl];
    if (mu > M) {
      const float sc = exp2f(M - mu);
      L = fmaf(L, sc, lu);
      A = fmaf(A, sc, au);
      M = mu;
    } else {
      const float e = exp2f(mu - M);
      L = fmaf(e, lu, L);
      A = fmaf(e, au, A);
    }
  }
  out[(size_t)cl * WH + wh] = A / L;
}

extern "C" void kernel_launch(void* const* d_in, const int* in_sizes, int n_in,
                              void* d_out, int out_size, void* d_ws, size_t ws_size,
                              hipStream_t stream)
{
  const float* X   = (const float*)d_in[0];
  const float* WQt = (const float*)d_in[1];
  const float* BQt = (const float*)d_in[2];
  const float* WKt = (const float*)d_in[3];
  const float* BKt = (const float*)d_in[4];
  const float* WVt = (const float*)d_in[5];
  const float* BVt = (const float*)d_in[6];
  const float* WQ1 = (const float*)d_in[7];
  const float* WQx = (const float*)d_in[8];
  const float* BQ  = (const float*)d_in[9];
  const float* WKx = (const float*)d_in[10];
  const float* BK  = (const float*)d_in[11];
  const float* Wc  = (const float*)d_in[12];
  const float* bc  = (const float*)d_in[13];
  const float* pQ  = (const float*)d_in[14];
  float* out = (float*)d_out;

  short8* qfrag = (short8*)d_ws;                      // 576*4*64 = 147456 recs
  short8* kfrag = qfrag + (size_t)147456;
  short8* vfrag = kfrag + (size_t)147456;             // 288*2*64 = 36864 recs
  short8* wfrag = vfrag + (size_t)36864;              // 2304 recs
  unsigned short* padXT = (unsigned short*)(wfrag + 2304);  // 9604*64 ushorts
  float* part = (float*)((char*)padXT + (size_t)PPLANE * 64 * 2);
  const size_t base_bytes = ((size_t)147456 * 2 + 36864 + 2304) * 16 + (size_t)PPLANE * 64 * 2;

  int ksplit = 8;
  while (ksplit > 1 &&
         base_bytes + (size_t)(4 * ksplit) * WH * 36 * sizeof(float) > ws_size)
    ksplit >>= 1;
  const int cps = 288 / ksplit;       // key-chunks per split
  const int units = 4 * ksplit;

  prep_kernel<<<dim3(878), 256, 0, stream>>>(X, WQt, BQt, WKt, BKt,
                                             WQ1, WQx, BQ, WKx, BK, pQ, Wc, WVt,
                                             (short*)qfrag, (short*)kfrag, padXT, wfrag);
  vconv_kernel<<<dim3(576), 256, 0, stream>>>(padXT, wfrag, bc, WVt, BVt, (short*)vfrag);
  flash_mfma<<<dim3(192, ksplit), 256, 0, stream>>>(qfrag, kfrag, vfrag, part, cps);
  merge_kernel<<<dim3(WH / 8), 256, 0, stream>>>(part, out, units);
}

// Round 9
// 81.077 us; speedup vs baseline: 1.4836x; 1.4836x over previous
//
#include <hip/hip_runtime.h>

#define WH 9216
#define NF 64
#define NC 32
#define NH 8
#define IMGW 96
#define IMGH 96
#define PW 98
#define PPLANE 9604
#define L2E 1.4426950408889634f
#define DEFER 11.5f   // log2 units

typedef float f32x4 __attribute__((ext_vector_type(4)));
typedef short short8 __attribute__((ext_vector_type(8)));

__device__ inline short bf16_bits(float x) {
  __bf16 h = (__bf16)x;
  return __builtin_bit_cast(short, h);
}
__device__ inline float bf16_round(float x) { return (float)(__bf16)x; }

// ---------------- kernel A (fused): qsk (blocks 0..575) + padX (576..876) + wpack (877) ----
__global__ __launch_bounds__(256, 2) void prep_kernel(
    const float* __restrict__ X, const float* __restrict__ WQ_task,
    const float* __restrict__ BQ_task, const float* __restrict__ WK_task,
    const float* __restrict__ BK_task, const float* __restrict__ WQ_t1,
    const float* __restrict__ WQ_x, const float* __restrict__ BQ,
    const float* __restrict__ WK_x, const float* __restrict__ BK,
    const float* __restrict__ prevQ, const float* __restrict__ Wc,
    const float* __restrict__ WV_task,
    short* __restrict__ qfrag, short* __restrict__ kfrag,
    unsigned short* __restrict__ padXT, short8* __restrict__ wfrag)
{
  const int bid = blockIdx.x;
  const int t = threadIdx.x;
  if (bid < 576) {
    const int lane = t & 63;
    const int w2 = t >> 6;
    const int fh = w2 & 1, sub = w2 >> 1;
    const int h = lane >> 4;
    const int T = bid;
    const int wh = T * 16 + (lane & 15);
    const int f0 = fh * 32 + 8 * h + 4 * sub;

    float x[4];
    #pragma unroll
    for (int e = 0; e < 4; ++e) x[e] = X[(size_t)(f0 + e) * WH + wh];
    float pq[32];
    #pragma unroll
    for (int a = 0; a < NH; ++a)
      #pragma unroll
      for (int e = 0; e < 4; ++e)
        pq[a * 4 + e] = prevQ[(size_t)(a * 64 + f0 + e) * WH + wh];

    const float4 wkx = *(const float4*)&WK_x[f0];
    const float4 bk  = *(const float4*)&BK[f0];
    const float4 wkt = *(const float4*)&WK_task[f0];
    const float4 bkt = *(const float4*)&BK_task[f0];
    const float4 wqx = *(const float4*)&WQ_x[f0];

    float q[4], k[4], xq[4];
    k[0] = fmaf(wkt.x, fmaxf(fmaf(wkx.x, x[0], bk.x), 0.f), bkt.x);
    k[1] = fmaf(wkt.y, fmaxf(fmaf(wkx.y, x[1], bk.y), 0.f), bkt.y);
    k[2] = fmaf(wkt.z, fmaxf(fmaf(wkx.z, x[2], bk.z), 0.f), bkt.z);
    k[3] = fmaf(wkt.w, fmaxf(fmaf(wkx.w, x[3], bk.w), 0.f), bkt.w);
    xq[0] = wqx.x * x[0]; xq[1] = wqx.y * x[1];
    xq[2] = wqx.z * x[2]; xq[3] = wqx.w * x[3];
    q[0] = q[1] = q[2] = q[3] = 0.f;
    #pragma unroll
    for (int a = 0; a < NH; ++a) {
      const int af0 = a * 64 + f0;
      const float4 w1  = *(const float4*)&WQ_t1[af0];
      const float4 bq  = *(const float4*)&BQ[af0];
      const float4 wqt = *(const float4*)&WQ_task[af0];
      const float4 bqt = *(const float4*)&BQ_task[af0];
      q[0] = fmaf(wqt.x, fmaxf(fmaf(w1.x, pq[a * 4 + 0], xq[0] + bq.x), 0.f), q[0]) + bqt.x;
      q[1] = fmaf(wqt.y, fmaxf(fmaf(w1.y, pq[a * 4 + 1], xq[1] + bq.y), 0.f), q[1]) + bqt.y;
      q[2] = fmaf(wqt.z, fmaxf(fmaf(w1.z, pq[a * 4 + 2], xq[2] + bq.z), 0.f), q[2]) + bqt.z;
      q[3] = fmaf(wqt.w, fmaxf(fmaf(w1.w, pq[a * 4 + 3], xq[3] + bq.w), 0.f), q[3]) + bqt.w;
    }

    short4 qh, ql, kh, klo;
    {
      float qs0 = q[0] * L2E, qs1 = q[1] * L2E, qs2 = q[2] * L2E, qs3 = q[3] * L2E;
      qh.x = bf16_bits(qs0); ql.x = bf16_bits(qs0 - bf16_round(qs0));
      qh.y = bf16_bits(qs1); ql.y = bf16_bits(qs1 - bf16_round(qs1));
      qh.z = bf16_bits(qs2); ql.z = bf16_bits(qs2 - bf16_round(qs2));
      qh.w = bf16_bits(qs3); ql.w = bf16_bits(qs3 - bf16_round(qs3));
      kh.x = bf16_bits(k[0]); klo.x = bf16_bits(k[0] - bf16_round(k[0]));
      kh.y = bf16_bits(k[1]); klo.y = bf16_bits(k[1] - bf16_round(k[1]));
      kh.z = bf16_bits(k[2]); klo.z = bf16_bits(k[2] - bf16_round(k[2]));
      kh.w = bf16_bits(k[3]); klo.w = bf16_bits(k[3] - bf16_round(k[3]));
    }
    const size_t offh = ((size_t)(T * 4 + fh) * 64 + lane) * 8 + sub * 4;
    const size_t offl = ((size_t)(T * 4 + 2 + fh) * 64 + lane) * 8 + sub * 4;
    *(short4*)&qfrag[offh] = qh;
    *(short4*)&qfrag[offl] = ql;
    *(short4*)&kfrag[offh] = kh;
    *(short4*)&kfrag[offl] = klo;
  } else if (bid < 877) {
    const int idx = (bid - 576) * 256 + t;        // fi*9604 + p, fi in [0,8)
    if (idx < 76832) {
      const int fi = idx / PPLANE;
      const int p = idx - fi * PPLANE;
      const int pw = p / PW;
      const int ph = p - pw * PW;
      short8 r;
      if (pw >= 1 && pw <= IMGW && ph >= 1 && ph <= IMGH) {
        const float* src = X + (size_t)fi * 8 * WH + (pw - 1) * IMGH + (ph - 1);
        #pragma unroll
        for (int e = 0; e < 8; ++e) r[e] = bf16_bits(src[(size_t)e * WH]);
      } else {
        #pragma unroll
        for (int e = 0; e < 8; ++e) r[e] = 0;
      }
      *(short8*)&padXT[(size_t)p * 64 + fi * 8] = r;
    }
  } else {
    #pragma unroll
    for (int j = 0; j < 9; ++j) {
      const int ridx = j * 256 + t;               // 2304 records
      const int ct = ridx / 1152;
      const int rem = ridx - ct * 1152;
      const int cc = rem >> 6;
      const int lane = rem & 63;
      const int c = ct * 16 + (lane & 15);
      const int tap = cc >> 1;
      const int f0 = (cc & 1) * 32 + 8 * (lane >> 4);
      const float wv = WV_task[c];
      short8 r;
      #pragma unroll
      for (int e = 0; e < 8; ++e)
        r[e] = bf16_bits(wv * Wc[((size_t)c * NF + f0 + e) * 9 + tap]);
      wfrag[ridx] = r;
    }
  }
}

// ---------------- kernel B: conv via MFMA; one 16-key tile per block, 4-way (Khalf,ct) split ----
__global__ __launch_bounds__(256, 2) void vconv_kernel(
    const unsigned short* __restrict__ padXT, const short8* __restrict__ wfrag,
    const float* __restrict__ bc, const float* __restrict__ WV_task,
    const float* __restrict__ BV_task, short* __restrict__ vfrag)
{
  __shared__ float Vt[2][32][20];
  const int t = threadIdx.x;
  const int lane = t & 63, w = t >> 6;
  const int h = lane >> 4;
  const int ktile = blockIdx.x;                 // 0..575
  const int half = w & 1, ct = w >> 1;
  const int key = ktile * 16 + (lane & 15);
  const int kw = key / IMGH, kh = key - kw * IMGH;

  f32x4 acc = {0.f, 0.f, 0.f, 0.f};
  #pragma unroll
  for (int i = 0; i < 9; ++i) {
    const int cc = half * 9 + i;
    const int tap = cc >> 1;
    const int di = tap / 3, dj = tap - di * 3;
    const int f0 = (cc & 1) * 32 + 8 * h;
    const int sp = (kw + di) * PW + (kh + dj);
    const short8 xf = *(const short8*)&padXT[(size_t)sp * 64 + f0];
    acc = __builtin_amdgcn_mfma_f32_16x16x32_bf16(wfrag[(size_t)(ct * 18 + cc) * 64 + lane],
                                                  xf, acc, 0, 0, 0);
  }
  #pragma unroll
  for (int reg = 0; reg < 4; ++reg)
    Vt[half][ct * 16 + 4 * h + reg][lane & 15] = acc[reg];
  __syncthreads();
  if (t < 128) {
    const int ct2 = t >> 6;
    const int c = ct2 * 16 + (lane & 15);
    const float bias = fmaf(WV_task[c], bc[c], BV_task[c]);
    short4 r;
    #pragma unroll
    for (int j = 0; j < 4; ++j) {
      const int kl = 4 * h + j;                 // baked pi-permutation half
      r[j] = bf16_bits(Vt[0][c][kl] + Vt[1][c][kl] + bias);
    }
    const int ch = ktile >> 1, eh = ktile & 1;
    *(short4*)&vfrag[(((size_t)ch * 2 + ct2) * 64 + lane) * 8 + eh * 4] = r;
  }
}

// ---------------- kernel C: MFMA flash, g=3, phase-batched (QK | softmax | PV) ----
__global__ __launch_bounds__(256, 3) void flash_mfma(
    const short8* __restrict__ qfrag, const short8* __restrict__ kfrag,
    const short8* __restrict__ vfrag, float* __restrict__ part, int cps)
{
  const int t = threadIdx.x;
  const int lane = t & 63, wave = t >> 6;
  const int h = lane >> 4;
  const int qb = blockIdx.x;     // 0..191 (fastest -> all XCDs share live K-slice)
  const int s = blockIdx.y;      // key split

  short8 qf[3][4];
  #pragma unroll
  for (int g = 0; g < 3; ++g)
    #pragma unroll
    for (int tm = 0; tm < 4; ++tm)
      qf[g][tm] = qfrag[((size_t)(qb * 3 + g) * 4 + tm) * 64 + lane];

  f32x4 acc[2][3];
  #pragma unroll
  for (int ct = 0; ct < 2; ++ct)
    #pragma unroll
    for (int g = 0; g < 3; ++g)
      acc[ct][g] = (f32x4){0.f, 0.f, 0.f, 0.f};
  float m[3] = {0.f, 0.f, 0.f};  // per-query running offset (uniform over h-lanes)
  float l[3] = {0.f, 0.f, 0.f};

  const int cpw = cps >> 2;
  const int ch0 = s * cps + wave;
  #pragma unroll 2
  for (int it = 0; it < cpw; ++it) {
    const int ch = ch0 + it * 4;
    short8 kf[2][4];
    #pragma unroll
    for (int kt = 0; kt < 2; ++kt)
      #pragma unroll
      for (int tm = 0; tm < 4; ++tm)
        kf[kt][tm] = kfrag[((size_t)(2 * ch + kt) * 4 + tm) * 64 + lane];
    const short8 vf0 = vfrag[(size_t)(ch * 2 + 0) * 64 + lane];
    const short8 vf1 = vfrag[(size_t)(ch * 2 + 1) * 64 + lane];

    // ---- PHASE 1: all QK MFMAs (3 independent 12-chains feed the matrix pipe) ----
    f32x4 st[3][2];
    __builtin_amdgcn_s_setprio(1);
    #pragma unroll
    for (int g = 0; g < 3; ++g) {
      const float nm = -m[g];
      f32x4 a0 = {nm, nm, nm, nm};
      f32x4 a1 = a0;
      a0 = __builtin_amdgcn_mfma_f32_16x16x32_bf16(kf[0][0], qf[g][0], a0, 0, 0, 0);
      a0 = __builtin_amdgcn_mfma_f32_16x16x32_bf16(kf[0][1], qf[g][1], a0, 0, 0, 0);
      a0 = __builtin_amdgcn_mfma_f32_16x16x32_bf16(kf[0][2], qf[g][0], a0, 0, 0, 0);
      a0 = __builtin_amdgcn_mfma_f32_16x16x32_bf16(kf[0][3], qf[g][1], a0, 0, 0, 0);
      a0 = __builtin_amdgcn_mfma_f32_16x16x32_bf16(kf[0][0], qf[g][2], a0, 0, 0, 0);
      a0 = __builtin_amdgcn_mfma_f32_16x16x32_bf16(kf[0][1], qf[g][3], a0, 0, 0, 0);
      a1 = __builtin_amdgcn_mfma_f32_16x16x32_bf16(kf[1][0], qf[g][0], a1, 0, 0, 0);
      a1 = __builtin_amdgcn_mfma_f32_16x16x32_bf16(kf[1][1], qf[g][1], a1, 0, 0, 0);
      a1 = __builtin_amdgcn_mfma_f32_16x16x32_bf16(kf[1][2], qf[g][0], a1, 0, 0, 0);
      a1 = __builtin_amdgcn_mfma_f32_16x16x32_bf16(kf[1][3], qf[g][1], a1, 0, 0, 0);
      a1 = __builtin_amdgcn_mfma_f32_16x16x32_bf16(kf[1][0], qf[g][2], a1, 0, 0, 0);
      a1 = __builtin_amdgcn_mfma_f32_16x16x32_bf16(kf[1][1], qf[g][3], a1, 0, 0, 0);
      st[g][0] = a0;
      st[g][1] = a1;
    }
    __builtin_amdgcn_s_setprio(0);

    // ---- PHASE 2: all softmaxes (pure VALU; other waves' phase-1 overlaps) ----
    short8 pb[3];
    #pragma unroll
    for (int g = 0; g < 3; ++g) {
      f32x4 st0 = st[g][0], st1 = st[g][1];
      const float loc = fmaxf(fmaxf(fmaxf(st0[0], st0[1]), fmaxf(st0[2], st0[3])),
                              fmaxf(fmaxf(st1[0], st1[1]), fmaxf(st1[2], st1[3])));
      if (__any(loc > DEFER)) {      // rare: per-query reduce + rescale
        float tr = loc;
        tr = fmaxf(tr, __shfl_xor(tr, 16));
        tr = fmaxf(tr, __shfl_xor(tr, 32));
        const float d = fmaxf(tr, 0.f);
        const float r = exp2f(-d);
        l[g] *= r;
        acc[0][g] *= r;
        acc[1][g] *= r;
        m[g] += d;
        #pragma unroll
        for (int e = 0; e < 4; ++e) { st0[e] -= d; st1[e] -= d; }
      }
      float p0[4], p1[4];
      #pragma unroll
      for (int e = 0; e < 4; ++e) {
        p0[e] = exp2f(st0[e]);
        p1[e] = exp2f(st1[e]);
        pb[g][e] = bf16_bits(p0[e]);
        pb[g][4 + e] = bf16_bits(p1[e]);
      }
      l[g] += ((p0[0] + p0[1]) + (p0[2] + p0[3])) + ((p1[0] + p1[1]) + (p1[2] + p1[3]));
    }

    // ---- PHASE 3: all PV MFMAs ----
    __builtin_amdgcn_s_setprio(1);
    #pragma unroll
    for (int g = 0; g < 3; ++g) {
      acc[0][g] = __builtin_amdgcn_mfma_f32_16x16x32_bf16(vf0, pb[g], acc[0][g], 0, 0, 0);
      acc[1][g] = __builtin_amdgcn_mfma_f32_16x16x32_bf16(vf1, pb[g], acc[1][g], 0, 0, 0);
    }
    __builtin_amdgcn_s_setprio(0);
  }

  // epilogue: per-wave partial record {acc[32], m, l}
  const int u = s * 4 + wave;
  #pragma unroll
  for (int g = 0; g < 3; ++g) {
    float lf = l[g] + __shfl_xor(l[g], 16);
    lf += __shfl_xor(lf, 32);
    const int q = qb * 48 + g * 16 + (lane & 15);
    float* base = part + ((size_t)u * WH + q) * 36;
    *(f32x4*)(base + 0 + 4 * h) = acc[0][g];
    *(f32x4*)(base + 16 + 4 * h) = acc[1][g];
    if (h == 0) { base[32] = m[g]; base[33] = lf; }
  }
}

// ---------------- kernel D: single-pass online merge -> out (C, W, H) ----------------
__global__ __launch_bounds__(256) void merge_kernel(
    const float* __restrict__ part, float* __restrict__ out, int units)
{
  const int t = threadIdx.x;
  const int cl = t & 31;
  const int wh = blockIdx.x * 8 + (t >> 5);
  float M = -1e30f, L = 0.f, A = 0.f;
  for (int u = 0; u < units; ++u) {
    const float* base = part + ((size_t)u * WH + wh) * 36;
    const float mu = base[32];
    const float lu = base[33];
    const float au = base[cl];
    if (mu > M) {
      const float sc = exp2f(M - mu);
      L = fmaf(L, sc, lu);
      A = fmaf(A, sc, au);
      M = mu;
    } else {
      const float e = exp2f(mu - M);
      L = fmaf(e, lu, L);
      A = fmaf(e, au, A);
    }
  }
  out[(size_t)cl * WH + wh] = A / L;
}

extern "C" void kernel_launch(void* const* d_in, const int* in_sizes, int n_in,
                              void* d_out, int out_size, void* d_ws, size_t ws_size,
                              hipStream_t stream)
{
  const float* X   = (const float*)d_in[0];
  const float* WQt = (const float*)d_in[1];
  const float* BQt = (const float*)d_in[2];
  const float* WKt = (const float*)d_in[3];
  const float* BKt = (const float*)d_in[4];
  const float* WVt = (const float*)d_in[5];
  const float* BVt = (const float*)d_in[6];
  const float* WQ1 = (const float*)d_in[7];
  const float* WQx = (const float*)d_in[8];
  const float* BQ  = (const float*)d_in[9];
  const float* WKx = (const float*)d_in[10];
  const float* BK  = (const float*)d_in[11];
  const float* Wc  = (const float*)d_in[12];
  const float* bc  = (const float*)d_in[13];
  const float* pQ  = (const float*)d_in[14];
  float* out = (float*)d_out;

  short8* qfrag = (short8*)d_ws;                      // 576*4*64 = 147456 recs
  short8* kfrag = qfrag + (size_t)147456;
  short8* vfrag = kfrag + (size_t)147456;             // 288*2*64 = 36864 recs
  short8* wfrag = vfrag + (size_t)36864;              // 2304 recs
  unsigned short* padXT = (unsigned short*)(wfrag + 2304);  // 9604*64 ushorts
  float* part = (float*)((char*)padXT + (size_t)PPLANE * 64 * 2);
  const size_t base_bytes = ((size_t)147456 * 2 + 36864 + 2304) * 16 + (size_t)PPLANE * 64 * 2;

  int ksplit = 4;
  while (ksplit > 1 &&
         base_bytes + (size_t)(4 * ksplit) * WH * 36 * sizeof(float) > ws_size)
    ksplit >>= 1;
  const int cps = 288 / ksplit;       // key-chunks per split
  const int units = 4 * ksplit;

  prep_kernel<<<dim3(878), 256, 0, stream>>>(X, WQt, BQt, WKt, BKt,
                                             WQ1, WQx, BQ, WKx, BK, pQ, Wc, WVt,
                                             (short*)qfrag, (short*)kfrag, padXT, wfrag);
  vconv_kernel<<<dim3(576), 256, 0, stream>>>(padXT, wfrag, bc, WVt, BVt, (short*)vfrag);
  flash_mfma<<<dim3(192, ksplit), 256, 0, stream>>>(qfrag, kfrag, vfrag, part, cps);
  merge_kernel<<<dim3(WH / 8), 256, 0, stream>>>(part, out, units);
}